// Round 8
// baseline (818.792 us; speedup 1.0000x reference)
//
#include <hip/hip_runtime.h>
#include <hip/hip_bf16.h>

#define NN 100000
#define NE 1600000
#define XD 4
#define ED 39
#define K1 43    // XD+ED
#define H1 64
#define H2 128
#define H3 256
#define NBN 32   // nodes per block in fused kernel (100000 = 3125*32)
#define NCHUNK 98  // ceil(NN/1024)

typedef short bfrag8 __attribute__((ext_vector_type(8)));
typedef float facc4  __attribute__((ext_vector_type(4)));
typedef unsigned short u16x4 __attribute__((ext_vector_type(4)));

// fp32 -> bf16 RNE via HW convert; bit-identical to software RNE bit-trick.
static __device__ __forceinline__ unsigned short f2bf(float f) {
    __hip_bfloat16 b = __float2bfloat16(f);
    union { __hip_bfloat16 b; unsigned short u; } v; v.b = b;
    return v.u;
}
static __device__ __forceinline__ float bf2f(unsigned short h) {
    union { unsigned int u; float f; } v; v.u = ((unsigned int)h) << 16;
    return v.f;
}

// ---------------- pass 1: indegree histogram + per-edge rank (counting-sort split)
__global__ __launch_bounds__(256) void hist_kernel(const int* __restrict__ eidx,
                                                   int* __restrict__ cnt,
                                                   int* __restrict__ rank) {
    int e = blockIdx.x * 256 + threadIdx.x;
    if (e < NE) rank[e] = atomicAdd(&cnt[eidx[e]], 1);
}

// ---------------- pass 2a: per-chunk local scan (98 blocks in parallel)
__global__ __launch_bounds__(1024) void scan1_kernel(const int* __restrict__ cnt,
                                                     int* __restrict__ row_ptr,
                                                     int* __restrict__ chunkSum) {
    __shared__ int wsum[16];
    const int t = threadIdx.x, lane = t & 63, w = t >> 6;
    const int i = blockIdx.x * 1024 + t;
    int v = (i < NN) ? cnt[i] : 0;
    int s = v;
    #pragma unroll
    for (int d = 1; d < 64; d <<= 1) {
        int u = __shfl_up(s, d, 64);
        if (lane >= d) s += u;
    }
    if (lane == 63) wsum[w] = s;
    __syncthreads();
    if (w == 0 && lane < 16) {
        int e = wsum[lane];
        #pragma unroll
        for (int d = 1; d < 16; d <<= 1) {
            int u = __shfl_up(e, d, 64);
            if (lane >= d) e += u;
        }
        wsum[lane] = e;
    }
    __syncthreads();
    int woff = (w == 0) ? 0 : wsum[w - 1];
    if (i < NN) row_ptr[i + 1] = woff + s;    // chunk-local inclusive
    if (t == 0) chunkSum[blockIdx.x] = wsum[15];
}

// ---------------- pass 2b: exclusive scan of 98 chunk sums (one wave)
__global__ __launch_bounds__(64) void scan2_kernel(const int* __restrict__ chunkSum,
                                                   int* __restrict__ chunkOff) {
    const int lane = threadIdx.x;
    int a = (lane < NCHUNK) ? chunkSum[lane] : 0;
    int b = (lane + 64 < NCHUNK) ? chunkSum[lane + 64] : 0;
    int sa = a;
    #pragma unroll
    for (int d = 1; d < 64; d <<= 1) {
        int u = __shfl_up(sa, d, 64);
        if (lane >= d) sa += u;
    }
    int totA = __shfl(sa, 63, 64);
    int sb = b;
    #pragma unroll
    for (int d = 1; d < 64; d <<= 1) {
        int u = __shfl_up(sb, d, 64);
        if (lane >= d) sb += u;
    }
    sb += totA;
    if (lane < NCHUNK) chunkOff[lane] = sa - a;
    if (lane + 64 < NCHUNK) chunkOff[lane + 64] = sb - b;
}

// ---------------- pass 2c: apply chunk offsets to row_ptr
__global__ __launch_bounds__(1024) void scan3_kernel(const int* __restrict__ chunkOff,
                                                     int* __restrict__ row_ptr) {
    const int i = blockIdx.x * 1024 + threadIdx.x;
    const int off = chunkOff[blockIdx.x];
    if (i < NN) row_ptr[i + 1] += off;
    if (i == 0) row_ptr[0] = 0;
}

// ---------------- pass 3: atomic-free scatter (uses precomputed rank)
__global__ __launch_bounds__(256) void build_kernel(const int* __restrict__ eidx,
                                                    const int* __restrict__ row_ptr,
                                                    const int* __restrict__ rank,
                                                    int* __restrict__ perm) {
    int e = blockIdx.x * 256 + threadIdx.x;
    if (e < NE) {
        int r = eidx[e];
        perm[row_ptr[r] + rank[e]] = e;
    }
}

// ---------------- pass 3.5: split weights into bf16 hi/lo planes in per-lane
// FRAGMENT order: plane[(group*64 + lane)*8 + j] -> consumer loads are coalesced.
//   W1: group = wid*2+ks               (8 groups)
//   W2: group = (wid*2+nt)*2+ks        (16 groups)
//   W3: group = (w*5+ks)*4+nt          (80 groups, k pad 132->160)
//   W4: group = (w*8+ks)*4+nt          (128 groups)
__global__ __launch_bounds__(256) void prep_kernel(
    const float* __restrict__ W1, const float* __restrict__ W2,
    const float* __restrict__ W3, const float* __restrict__ W4,
    unsigned short* __restrict__ W1h, unsigned short* __restrict__ W1l,
    unsigned short* __restrict__ W2h, unsigned short* __restrict__ W2l,
    unsigned short* __restrict__ W3h, unsigned short* __restrict__ W3l,
    unsigned short* __restrict__ W4h, unsigned short* __restrict__ W4l)
{
    int i = blockIdx.x * 256 + threadIdx.x;
    if (i >= 4096 + 8192 + 40960 + 65536) return;
    unsigned short *ph, *pl;
    int idx, col, k;
    float w;
    if (i < 4096) {
        idx = i;
        int grp = idx >> 9, lane = (idx >> 3) & 63, j = idx & 7;
        int wid = grp >> 1, ks = grp & 1;
        col = wid * 16 + (lane & 15);
        k   = ks * 32 + (lane >> 4) * 8 + j;
        w = (k < K1) ? W1[k * H1 + col] : 0.f;
        ph = W1h; pl = W1l;
    } else if (i < 12288) {
        idx = i - 4096;
        int grp = idx >> 9, lane = (idx >> 3) & 63, j = idx & 7;
        int wid = grp >> 2, nt = (grp >> 1) & 1, ks = grp & 1;
        col = wid * 32 + nt * 16 + (lane & 15);
        k   = ks * 32 + (lane >> 4) * 8 + j;
        w = W2[k * H2 + col];
        ph = W2h; pl = W2l;
    } else if (i < 53248) {
        idx = i - 12288;
        int grp = idx >> 9, lane = (idx >> 3) & 63, j = idx & 7;
        int w_ = grp / 20, rem = grp - w_ * 20;
        int ks = rem >> 2, nt = rem & 3;
        col = w_ * 64 + nt * 16 + (lane & 15);
        k   = ks * 32 + (lane >> 4) * 8 + j;
        w = (k < 132) ? W3[k * H3 + col] : 0.f;
        ph = W3h; pl = W3l;
    } else {
        idx = i - 53248;
        int grp = idx >> 9, lane = (idx >> 3) & 63, j = idx & 7;
        int w_ = grp >> 5, rem = grp & 31;
        int ks = rem >> 2, nt = rem & 3;
        col = w_ * 64 + nt * 16 + (lane & 15);
        k   = ks * 32 + (lane >> 4) * 8 + j;
        w = W4[k * H3 + col];
        ph = W4h; pl = W4l;
    }
    unsigned short h = f2bf(w);
    ph[idx] = h;
    pl[idx] = f2bf(w - bf2f(h));
}

// ---------------- pass 4: FUSED edge MLP + selector segment-mean + node MLP.
// NBN=32 (halves per-block fixed costs vs 16). 4 barriers/tile: the old s4
// (between H2T write and selector read) is removed — wave wid writes H2T cols
// [wid*32, wid*32+32) in P3 and reads exactly those cols in P4 (intra-wave LDS
// dependency, ordered by lgkmcnt; no cross-wave hazard). s5 stays: next-tile P0
// overwrites the H2T region for ALL waves.
__global__ __launch_bounds__(256, 3) void edge_agg_kernel(
    const float* __restrict__ x, const int* __restrict__ eidx,
    const float* __restrict__ ea,
    const unsigned short* __restrict__ W1h, const unsigned short* __restrict__ W1l,
    const float* __restrict__ b1,
    const unsigned short* __restrict__ W2h, const unsigned short* __restrict__ W2l,
    const float* __restrict__ b2,
    const unsigned short* __restrict__ W3h, const unsigned short* __restrict__ W3l,
    const float* __restrict__ b3,
    const unsigned short* __restrict__ W4h, const unsigned short* __restrict__ W4l,
    const float* __restrict__ b4,
    const int* __restrict__ row_ptr, const int* __restrict__ perm,
    float* __restrict__ out)
{
    // uMem union: tile loop {Ahi|Alo|H1hi|H1lo [64][72] each} / {H2T hi|lo [128][72]}
    // epilogue: nA [32][168] hi/lo (10752 sh); then (after barrier) H [32][264] hi/lo
    __shared__ __align__(16) unsigned short uMem[4 * 64 * 72];     // 36864 B
    __shared__ __align__(16) int sNode[64];
    __shared__ int sPerm[2][64], sCol[2][64], sRP[NBN + 1];

    unsigned short* Ahi   = uMem;
    unsigned short* Alo   = uMem + 64 * 72;
    unsigned short* H1hi  = uMem + 2 * 64 * 72;
    unsigned short* H1lo  = uMem + 3 * 64 * 72;
    unsigned short* H2Thi = uMem;                 // [128][72]
    unsigned short* H2Tlo = uMem + 128 * 72;
    unsigned short* nAh   = uMem;                 // [32][168]
    unsigned short* nAl   = uMem + 32 * 168;
    unsigned short* Hh    = uMem;                 // [32][264] (after barrier)
    unsigned short* Hl    = uMem + 32 * 264;

    const int t    = threadIdx.x;
    const int lane = t & 63;
    const int wid  = t >> 6;
    const int cl   = lane & 15;
    const int lg   = lane >> 4;
    const int n0   = blockIdx.x * NBN;

    // issue tile-0 perm/col loads first
    int p0 = -1, c0 = 0;
    if (t < 64) {
        int b0  = row_ptr[n0];
        int e0r = row_ptr[n0 + NBN];
        if (b0 + t < e0r) p0 = perm[b0 + t];
        if (p0 >= 0) c0 = eidx[NE + p0];
    }

    if (t <= NBN) sRP[t] = row_ptr[n0 + t];

    // register-resident weight fragments (coalesced fragment-order layout)
    bfrag8 w1h_[2], w1l_[2], w2h_[2][2], w2l_[2][2];
    #pragma unroll
    for (int ks = 0; ks < 2; ks++) {
        const int off = ((wid * 2 + ks) * 64 + lane) * 8;
        w1h_[ks] = *(const bfrag8*)&W1h[off];
        w1l_[ks] = *(const bfrag8*)&W1l[off];
    }
    #pragma unroll
    for (int nt = 0; nt < 2; nt++)
        #pragma unroll
        for (int ks = 0; ks < 2; ks++) {
            const int off = (((wid * 2 + nt) * 2 + ks) * 64 + lane) * 8;
            w2h_[nt][ks] = *(const bfrag8*)&W2h[off];
            w2l_[nt][ks] = *(const bfrag8*)&W2l[off];
        }
    const float bias1 = b1[wid * 16 + cl];
    const float bias2[2] = { b2[wid * 32 + cl], b2[wid * 32 + 16 + cl] };

    // persistent per-node accumulator: [sg node-group 0/1][nt]; wave wid owns
    // cols [wid*32, wid*32+32); element j of [sg][nt] = node sg*16+lg*4+j
    facc4 acc_sel[2][2];
    #pragma unroll
    for (int sg = 0; sg < 2; sg++)
        #pragma unroll
        for (int nt = 0; nt < 2; nt++) {
            acc_sel[sg][nt][0] = 0.f; acc_sel[sg][nt][1] = 0.f;
            acc_sel[sg][nt][2] = 0.f; acc_sel[sg][nt][3] = 0.f;
        }

    if (t < 64) { sPerm[0][t] = p0; sCol[0][t] = c0; }
    __syncthreads();

    const int base = sRP[0], cntE = sRP[NBN] - base;

    auto loadA = [&](float (&pv)[4][4], const int* sP, const int* sC) {
        #pragma unroll
        for (int r = 0; r < 4; r++) {
            const int e  = (t >> 4) + r * 16;
            const int k0 = (t & 15) * 4;
            const int ee = sP[e];
            if (ee >= 0) {
                if (k0 == 0) {
                    float4 xv = *(const float4*)&x[(size_t)sC[e] * XD];
                    pv[r][0] = xv.x; pv[r][1] = xv.y; pv[r][2] = xv.z; pv[r][3] = xv.w;
                } else {
                    const float* er = ea + (size_t)ee * ED;
                    #pragma unroll
                    for (int q = 0; q < 4; q++) {
                        int k = k0 + q;
                        pv[r][q] = (k < K1) ? er[k - XD] : 0.f;
                    }
                }
            } else {
                pv[r][0] = pv[r][1] = pv[r][2] = pv[r][3] = 0.f;
            }
        }
    };

    if (cntE > 0) {
        float pv[4][4];
        loadA(pv, sPerm[0], sCol[0]);
        int buf = 0;

        for (int tb = 0; tb < cntE; tb += 64) {
            const int nv   = min(64, cntE - tb);
            const int nbuf = buf ^ 1;

            int pp = -1;
            if (t < 64 && tb + 64 < cntE)
                pp = (tb + 64 + t < cntE) ? perm[base + tb + 64 + t] : -1;

            // ---- P0: stage A (overlays H2T; prev selector phase done at s5)
            #pragma unroll
            for (int r = 0; r < 4; r++) {
                const int e  = (t >> 4) + r * 16;
                const int k0 = (t & 15) * 4;
                u16x4 hv, lv;
                #pragma unroll
                for (int q = 0; q < 4; q++) {
                    unsigned short h = f2bf(pv[r][q]);
                    hv[q] = h;
                    lv[q] = f2bf(pv[r][q] - bf2f(h));
                }
                *(u16x4*)&Ahi[e * 72 + k0] = hv;
                *(u16x4*)&Alo[e * 72 + k0] = lv;
            }
            if (t < 64) {
                int nd = -1;
                if (t < nv) {
                    int idx = tb + t;
                    nd = 0;
                    #pragma unroll
                    for (int k = 1; k < NBN; k++) nd += ((sRP[k] - base) <= idx);
                }
                sNode[t] = nd;
            }
            __syncthreads();                                   // s1

            int pc = 0;
            if (t < 64 && pp >= 0) pc = eidx[NE + pp];

            // ---- P1: layer 1
            facc4 acc1[4];
            #pragma unroll
            for (int mt = 0; mt < 4; mt++) {
                acc1[mt][0] = bias1; acc1[mt][1] = bias1;
                acc1[mt][2] = bias1; acc1[mt][3] = bias1;
            }
            #pragma unroll
            for (int ks = 0; ks < 2; ks++) {
                #pragma unroll
                for (int mt = 0; mt < 4; mt++) {
                    const int ao = (mt * 16 + cl) * 72 + ks * 32 + lg * 8;
                    bfrag8 ah = *(const bfrag8*)&Ahi[ao];
                    bfrag8 al = *(const bfrag8*)&Alo[ao];
                    acc1[mt] = __builtin_amdgcn_mfma_f32_16x16x32_bf16(ah, w1h_[ks], acc1[mt], 0, 0, 0);
                    acc1[mt] = __builtin_amdgcn_mfma_f32_16x16x32_bf16(al, w1h_[ks], acc1[mt], 0, 0, 0);
                    acc1[mt] = __builtin_amdgcn_mfma_f32_16x16x32_bf16(ah, w1l_[ks], acc1[mt], 0, 0, 0);
                }
            }
            #pragma unroll
            for (int mt = 0; mt < 4; mt++)
                #pragma unroll
                for (int j = 0; j < 4; j++) {
                    float v = fmaxf(acc1[mt][j], 0.f);
                    unsigned short h = f2bf(v);
                    int m = mt * 16 + lg * 4 + j;
                    H1hi[m * 72 + wid * 16 + cl] = h;
                    H1lo[m * 72 + wid * 16 + cl] = f2bf(v - bf2f(h));
                }
            if (t < 64) { sPerm[nbuf][t] = pp; sCol[nbuf][t] = pc; }
            __syncthreads();                                   // s2

            // prefetch next tile's A values (overlaps L2 + H2T + selector phases)
            if (tb + 64 < cntE) loadA(pv, sPerm[nbuf], sCol[nbuf]);

            // ---- P2: layer 2
            facc4 acc2[4][2];
            #pragma unroll
            for (int mt = 0; mt < 4; mt++)
                #pragma unroll
                for (int nt = 0; nt < 2; nt++) {
                    acc2[mt][nt][0] = bias2[nt]; acc2[mt][nt][1] = bias2[nt];
                    acc2[mt][nt][2] = bias2[nt]; acc2[mt][nt][3] = bias2[nt];
                }
            #pragma unroll
            for (int ks = 0; ks < 2; ks++) {
                #pragma unroll
                for (int mt = 0; mt < 4; mt++) {
                    const int ao = (mt * 16 + cl) * 72 + ks * 32 + lg * 8;
                    bfrag8 ah = *(const bfrag8*)&H1hi[ao];
                    bfrag8 al = *(const bfrag8*)&H1lo[ao];
                    #pragma unroll
                    for (int nt = 0; nt < 2; nt++) {
                        acc2[mt][nt] = __builtin_amdgcn_mfma_f32_16x16x32_bf16(ah, w2h_[nt][ks], acc2[mt][nt], 0, 0, 0);
                        acc2[mt][nt] = __builtin_amdgcn_mfma_f32_16x16x32_bf16(al, w2h_[nt][ks], acc2[mt][nt], 0, 0, 0);
                        acc2[mt][nt] = __builtin_amdgcn_mfma_f32_16x16x32_bf16(ah, w2l_[nt][ks], acc2[mt][nt], 0, 0, 0);
                    }
                }
            }
            __syncthreads();                                   // s3: all uMem reads done

            // ---- P3: write relu(h2) hi/lo transposed [col][edge] (wave-private cols)
            #pragma unroll
            for (int mt = 0; mt < 4; mt++)
                #pragma unroll
                for (int nt = 0; nt < 2; nt++) {
                    const int c2 = wid * 32 + nt * 16 + cl;
                    u16x4 hv, lv;
                    #pragma unroll
                    for (int j = 0; j < 4; j++) {
                        float v = fmaxf(acc2[mt][nt][j], 0.f);
                        unsigned short h = f2bf(v);
                        hv[j] = h;
                        lv[j] = f2bf(v - bf2f(h));
                    }
                    const int eb = mt * 16 + lg * 4;
                    *(u16x4*)&H2Thi[c2 * 72 + eb] = hv;
                    *(u16x4*)&H2Tlo[c2 * 72 + eb] = lv;
                }
            // (no barrier: P4 reads only this wave's own columns)

            // ---- P4: selector MFMA — acc[sg][nt] += SEL_sg @ (H2hi + H2lo)
            #pragma unroll
            for (int ks = 0; ks < 2; ks++) {
                const int4* np = (const int4*)&sNode[ks * 32 + lg * 8];
                int4 na = np[0], nb = np[1];        // broadcast reads, conflict-free
                bfrag8 sf0, sf1;
                sf0[0] = (na.x == cl)      ? (short)0x3F80 : (short)0;
                sf0[1] = (na.y == cl)      ? (short)0x3F80 : (short)0;
                sf0[2] = (na.z == cl)      ? (short)0x3F80 : (short)0;
                sf0[3] = (na.w == cl)      ? (short)0x3F80 : (short)0;
                sf0[4] = (nb.x == cl)      ? (short)0x3F80 : (short)0;
                sf0[5] = (nb.y == cl)      ? (short)0x3F80 : (short)0;
                sf0[6] = (nb.z == cl)      ? (short)0x3F80 : (short)0;
                sf0[7] = (nb.w == cl)      ? (short)0x3F80 : (short)0;
                sf1[0] = (na.x == cl + 16) ? (short)0x3F80 : (short)0;
                sf1[1] = (na.y == cl + 16) ? (short)0x3F80 : (short)0;
                sf1[2] = (na.z == cl + 16) ? (short)0x3F80 : (short)0;
                sf1[3] = (na.w == cl + 16) ? (short)0x3F80 : (short)0;
                sf1[4] = (nb.x == cl + 16) ? (short)0x3F80 : (short)0;
                sf1[5] = (nb.y == cl + 16) ? (short)0x3F80 : (short)0;
                sf1[6] = (nb.z == cl + 16) ? (short)0x3F80 : (short)0;
                sf1[7] = (nb.w == cl + 16) ? (short)0x3F80 : (short)0;
                #pragma unroll
                for (int nt = 0; nt < 2; nt++) {
                    const int hb = (wid * 32 + nt * 16 + cl) * 72 + ks * 32 + lg * 8;
                    bfrag8 hh = *(const bfrag8*)&H2Thi[hb];
                    bfrag8 hl = *(const bfrag8*)&H2Tlo[hb];
                    acc_sel[0][nt] = __builtin_amdgcn_mfma_f32_16x16x32_bf16(sf0, hh, acc_sel[0][nt], 0, 0, 0);
                    acc_sel[0][nt] = __builtin_amdgcn_mfma_f32_16x16x32_bf16(sf0, hl, acc_sel[0][nt], 0, 0, 0);
                    acc_sel[1][nt] = __builtin_amdgcn_mfma_f32_16x16x32_bf16(sf1, hh, acc_sel[1][nt], 0, 0, 0);
                    acc_sel[1][nt] = __builtin_amdgcn_mfma_f32_16x16x32_bf16(sf1, hl, acc_sel[1][nt], 0, 0, 0);
                }
            }
            __syncthreads();                                   // s5: uMem reads done
            buf = nbuf;
        }
    }

    // ================= node-MLP epilogue (32 nodes) =================
    __syncthreads();   // uniform; protects uMem overlay

    // stage nA = [x(4) | mean(128) | 0-pad(28)] hi/lo from registers
    #pragma unroll
    for (int sg = 0; sg < 2; sg++)
        #pragma unroll
        for (int nt = 0; nt < 2; nt++)
            #pragma unroll
            for (int j = 0; j < 4; j++) {
                const int n = sg * 16 + lg * 4 + j;
                const int deg = sRP[n + 1] - sRP[n];
                const float inv = (deg > 0) ? 1.f / (float)deg : 0.f;
                const float m = acc_sel[sg][nt][j] * inv;
                unsigned short h = f2bf(m);
                const int k = 4 + wid * 32 + nt * 16 + cl;
                nAh[n * 168 + k] = h;
                nAl[n * 168 + k] = f2bf(m - bf2f(h));
            }
    if (t < 128) {
        const int n = t >> 2, k = t & 3;
        float xv = x[(size_t)(n0 + n) * XD + k];
        unsigned short h = f2bf(xv);
        nAh[n * 168 + k] = h;
        nAl[n * 168 + k] = f2bf(xv - bf2f(h));
    }
    for (int i = t; i < 896; i += 256) {       // k in [132,160), 32 nodes
        int n = i / 28, k = 132 + (i - n * 28);
        nAh[n * 168 + k] = 0;
        nAl[n * 168 + k] = 0;
    }
    __syncthreads();

    // GEMM1: [32 x 160] @ [160 x 256]; wave wid owns cols [wid*64, wid*64+64)
    facc4 na_[2][4];
    #pragma unroll
    for (int nt = 0; nt < 4; nt++) {
        float b = b3[wid * 64 + nt * 16 + cl];
        #pragma unroll
        for (int mt = 0; mt < 2; mt++) {
            na_[mt][nt][0] = b; na_[mt][nt][1] = b;
            na_[mt][nt][2] = b; na_[mt][nt][3] = b;
        }
    }
    #pragma unroll
    for (int ks = 0; ks < 5; ks++) {
        bfrag8 ah[2], al[2];
        #pragma unroll
        for (int mt = 0; mt < 2; mt++) {
            const int ao = (mt * 16 + cl) * 168 + ks * 32 + lg * 8;
            ah[mt] = *(const bfrag8*)&nAh[ao];
            al[mt] = *(const bfrag8*)&nAl[ao];
        }
        #pragma unroll
        for (int nt = 0; nt < 4; nt++) {
            const int wo = (((wid * 5 + ks) * 4 + nt) * 64 + lane) * 8;
            bfrag8 bh = *(const bfrag8*)&W3h[wo];
            bfrag8 bl = *(const bfrag8*)&W3l[wo];
            #pragma unroll
            for (int mt = 0; mt < 2; mt++) {
                na_[mt][nt] = __builtin_amdgcn_mfma_f32_16x16x32_bf16(ah[mt], bh, na_[mt][nt], 0, 0, 0);
                na_[mt][nt] = __builtin_amdgcn_mfma_f32_16x16x32_bf16(al[mt], bh, na_[mt][nt], 0, 0, 0);
                na_[mt][nt] = __builtin_amdgcn_mfma_f32_16x16x32_bf16(ah[mt], bl, na_[mt][nt], 0, 0, 0);
            }
        }
    }
    __syncthreads();   // nA reads done -> H may overlay

    #pragma unroll
    for (int mt = 0; mt < 2; mt++)
        #pragma unroll
        for (int nt = 0; nt < 4; nt++)
            #pragma unroll
            for (int j = 0; j < 4; j++) {
                float v = fmaxf(na_[mt][nt][j], 0.f);
                const int r = mt * 16 + lg * 4 + j;
                const int c = wid * 64 + nt * 16 + cl;
                unsigned short h = f2bf(v);
                Hh[r * 264 + c] = h;
                Hl[r * 264 + c] = f2bf(v - bf2f(h));
            }
    __syncthreads();

    // GEMM2: [32 x 256] @ [256 x 256] -> out
    facc4 nb_[2][4];
    #pragma unroll
    for (int nt = 0; nt < 4; nt++) {
        float b = b4[wid * 64 + nt * 16 + cl];
        #pragma unroll
        for (int mt = 0; mt < 2; mt++) {
            nb_[mt][nt][0] = b; nb_[mt][nt][1] = b;
            nb_[mt][nt][2] = b; nb_[mt][nt][3] = b;
        }
    }
    #pragma unroll
    for (int ks = 0; ks < 8; ks++) {
        bfrag8 ah[2], al[2];
        #pragma unroll
        for (int mt = 0; mt < 2; mt++) {
            const int ao = (mt * 16 + cl) * 264 + ks * 32 + lg * 8;
            ah[mt] = *(const bfrag8*)&Hh[ao];
            al[mt] = *(const bfrag8*)&Hl[ao];
        }
        #pragma unroll
        for (int nt = 0; nt < 4; nt++) {
            const int wo = (((wid * 8 + ks) * 4 + nt) * 64 + lane) * 8;
            bfrag8 bh = *(const bfrag8*)&W4h[wo];
            bfrag8 bl = *(const bfrag8*)&W4l[wo];
            #pragma unroll
            for (int mt = 0; mt < 2; mt++) {
                nb_[mt][nt] = __builtin_amdgcn_mfma_f32_16x16x32_bf16(ah[mt], bh, nb_[mt][nt], 0, 0, 0);
                nb_[mt][nt] = __builtin_amdgcn_mfma_f32_16x16x32_bf16(al[mt], bh, nb_[mt][nt], 0, 0, 0);
                nb_[mt][nt] = __builtin_amdgcn_mfma_f32_16x16x32_bf16(ah[mt], bl, nb_[mt][nt], 0, 0, 0);
            }
        }
    }
    #pragma unroll
    for (int mt = 0; mt < 2; mt++)
        #pragma unroll
        for (int nt = 0; nt < 4; nt++)
            #pragma unroll
            for (int j = 0; j < 4; j++)
                out[(size_t)(n0 + mt * 16 + lg * 4 + j) * H3 + wid * 64 + nt * 16 + cl] =
                    fmaxf(nb_[mt][nt][j], 0.f);
}

extern "C" void kernel_launch(void* const* d_in, const int* in_sizes, int n_in,
                              void* d_out, int out_size, void* d_ws, size_t ws_size,
                              hipStream_t stream) {
    const float* x    = (const float*)d_in[0];
    const int*   eidx = (const int*)  d_in[1];
    const float* ea   = (const float*)d_in[2];
    const float* W1   = (const float*)d_in[3];
    const float* b1   = (const float*)d_in[4];
    const float* W2   = (const float*)d_in[5];
    const float* b2   = (const float*)d_in[6];
    const float* W3   = (const float*)d_in[7];
    const float* b3   = (const float*)d_in[8];
    const float* W4   = (const float*)d_in[9];
    const float* b4   = (const float*)d_in[10];
    float* out = (float*)d_out;

    char* p = (char*)d_ws;
    int* perm     = (int*)p;  p += (size_t)NE * 4;
    int* rank     = (int*)p;  p += (size_t)NE * 4;          // dead after build
    int* row_ptr  = (int*)p;  p += ((size_t)NN + 8) * 4;
    int* cnt      = (int*)p;  p += (size_t)NN * 4;          // dead after scan1
    int* chunkSum = (int*)p;  p += 128 * 4;
    int* chunkOff = (int*)p;  p += 128 * 4;

    // weight bf16 hi/lo planes overlay rank (6.4 MB; dead after build_kernel)
    unsigned short* wp = (unsigned short*)rank;
    unsigned short* W1h_ = wp; wp += 64 * 64;
    unsigned short* W1l_ = wp; wp += 64 * 64;
    unsigned short* W2h_ = wp; wp += 128 * 64;
    unsigned short* W2l_ = wp; wp += 128 * 64;
    unsigned short* W3h_ = wp; wp += 256 * 160;
    unsigned short* W3l_ = wp; wp += 256 * 160;
    unsigned short* W4h_ = wp; wp += 256 * 256;
    unsigned short* W4l_ = wp; wp += 256 * 256;   // total 475136 B < 6.4 MB

    hipMemsetAsync(cnt, 0, (size_t)NN * 4, stream);

    hist_kernel <<<(NE + 255) / 256, 256, 0, stream>>>(eidx, cnt, rank);
    scan1_kernel<<<NCHUNK, 1024, 0, stream>>>(cnt, row_ptr, chunkSum);
    scan2_kernel<<<1, 64, 0, stream>>>(chunkSum, chunkOff);
    scan3_kernel<<<NCHUNK, 1024, 0, stream>>>(chunkOff, row_ptr);
    build_kernel<<<(NE + 255) / 256, 256, 0, stream>>>(eidx, row_ptr, rank, perm);
    prep_kernel <<<(4096 + 8192 + 40960 + 65536 + 255) / 256, 256, 0, stream>>>(
        W1, W2, W3, W4, W1h_, W1l_, W2h_, W2l_, W3h_, W3l_, W4h_, W4l_);
    edge_agg_kernel<<<NN / NBN, 256, 0, stream>>>(
        x, eidx, ea, W1h_, W1l_, b1, W2h_, W2l_, b2,
        W3h_, W3l_, b3, W4h_, W4l_, b4, row_ptr, perm, out);
}

// Round 9
// 777.850 us; speedup vs baseline: 1.0526x; 1.0526x over previous
//
#include <hip/hip_runtime.h>
#include <hip/hip_bf16.h>

#define NN 100000
#define NE 1600000
#define XD 4
#define ED 39
#define K1 43    // XD+ED
#define H1 64
#define H2 128
#define H3 256
#define NBN 16   // nodes per block (r8's NBN=32 doubled persistent regs -> spills, +300MB HBM)
#define NCHUNK 98  // ceil(NN/1024)

typedef short bfrag8 __attribute__((ext_vector_type(8)));
typedef float facc4  __attribute__((ext_vector_type(4)));
typedef unsigned short u16x4 __attribute__((ext_vector_type(4)));

// fp32 -> bf16 RNE via HW convert; bit-identical to software RNE bit-trick.
static __device__ __forceinline__ unsigned short f2bf(float f) {
    __hip_bfloat16 b = __float2bfloat16(f);
    union { __hip_bfloat16 b; unsigned short u; } v; v.b = b;
    return v.u;
}
static __device__ __forceinline__ float bf2f(unsigned short h) {
    union { unsigned int u; float f; } v; v.u = ((unsigned int)h) << 16;
    return v.f;
}

// ---------------- pass 1: indegree histogram + per-edge rank (counting-sort split)
__global__ __launch_bounds__(256) void hist_kernel(const int* __restrict__ eidx,
                                                   int* __restrict__ cnt,
                                                   int* __restrict__ rank) {
    int e = blockIdx.x * 256 + threadIdx.x;
    if (e < NE) rank[e] = atomicAdd(&cnt[eidx[e]], 1);
}

// ---------------- pass 2a: per-chunk local scan (98 blocks in parallel)
__global__ __launch_bounds__(1024) void scan1_kernel(const int* __restrict__ cnt,
                                                     int* __restrict__ row_ptr,
                                                     int* __restrict__ chunkSum) {
    __shared__ int wsum[16];
    const int t = threadIdx.x, lane = t & 63, w = t >> 6;
    const int i = blockIdx.x * 1024 + t;
    int v = (i < NN) ? cnt[i] : 0;
    int s = v;
    #pragma unroll
    for (int d = 1; d < 64; d <<= 1) {
        int u = __shfl_up(s, d, 64);
        if (lane >= d) s += u;
    }
    if (lane == 63) wsum[w] = s;
    __syncthreads();
    if (w == 0 && lane < 16) {
        int e = wsum[lane];
        #pragma unroll
        for (int d = 1; d < 16; d <<= 1) {
            int u = __shfl_up(e, d, 64);
            if (lane >= d) e += u;
        }
        wsum[lane] = e;
    }
    __syncthreads();
    int woff = (w == 0) ? 0 : wsum[w - 1];
    if (i < NN) row_ptr[i + 1] = woff + s;    // chunk-local inclusive
    if (t == 0) chunkSum[blockIdx.x] = wsum[15];
}

// ---------------- pass 2b: exclusive scan of 98 chunk sums (one wave)
__global__ __launch_bounds__(64) void scan2_kernel(const int* __restrict__ chunkSum,
                                                   int* __restrict__ chunkOff) {
    const int lane = threadIdx.x;
    int a = (lane < NCHUNK) ? chunkSum[lane] : 0;
    int b = (lane + 64 < NCHUNK) ? chunkSum[lane + 64] : 0;
    int sa = a;
    #pragma unroll
    for (int d = 1; d < 64; d <<= 1) {
        int u = __shfl_up(sa, d, 64);
        if (lane >= d) sa += u;
    }
    int totA = __shfl(sa, 63, 64);
    int sb = b;
    #pragma unroll
    for (int d = 1; d < 64; d <<= 1) {
        int u = __shfl_up(sb, d, 64);
        if (lane >= d) sb += u;
    }
    sb += totA;
    if (lane < NCHUNK) chunkOff[lane] = sa - a;
    if (lane + 64 < NCHUNK) chunkOff[lane + 64] = sb - b;
}

// ---------------- pass 2c: apply chunk offsets to row_ptr
__global__ __launch_bounds__(1024) void scan3_kernel(const int* __restrict__ chunkOff,
                                                     int* __restrict__ row_ptr) {
    const int i = blockIdx.x * 1024 + threadIdx.x;
    const int off = chunkOff[blockIdx.x];
    if (i < NN) row_ptr[i + 1] += off;
    if (i == 0) row_ptr[0] = 0;
}

// ---------------- pass 3: atomic-free scatter (uses precomputed rank)
__global__ __launch_bounds__(256) void build_kernel(const int* __restrict__ eidx,
                                                    const int* __restrict__ row_ptr,
                                                    const int* __restrict__ rank,
                                                    int* __restrict__ perm) {
    int e = blockIdx.x * 256 + threadIdx.x;
    if (e < NE) {
        int r = eidx[e];
        perm[row_ptr[r] + rank[e]] = e;
    }
}

// ---------------- pass 3.5: split weights into bf16 hi/lo planes in per-lane
// FRAGMENT order: plane[(group*64 + lane)*8 + j] -> consumer loads are coalesced.
//   W1: group = wid*2+ks               (8 groups)
//   W2: group = (wid*2+nt)*2+ks        (16 groups)
//   W3: group = (w*5+ks)*4+nt          (80 groups, k pad 132->160)
//   W4: group = (w*8+ks)*4+nt          (128 groups)
__global__ __launch_bounds__(256) void prep_kernel(
    const float* __restrict__ W1, const float* __restrict__ W2,
    const float* __restrict__ W3, const float* __restrict__ W4,
    unsigned short* __restrict__ W1h, unsigned short* __restrict__ W1l,
    unsigned short* __restrict__ W2h, unsigned short* __restrict__ W2l,
    unsigned short* __restrict__ W3h, unsigned short* __restrict__ W3l,
    unsigned short* __restrict__ W4h, unsigned short* __restrict__ W4l)
{
    int i = blockIdx.x * 256 + threadIdx.x;
    if (i >= 4096 + 8192 + 40960 + 65536) return;
    unsigned short *ph, *pl;
    int idx, col, k;
    float w;
    if (i < 4096) {
        idx = i;
        int grp = idx >> 9, lane = (idx >> 3) & 63, j = idx & 7;
        int wid = grp >> 1, ks = grp & 1;
        col = wid * 16 + (lane & 15);
        k   = ks * 32 + (lane >> 4) * 8 + j;
        w = (k < K1) ? W1[k * H1 + col] : 0.f;
        ph = W1h; pl = W1l;
    } else if (i < 12288) {
        idx = i - 4096;
        int grp = idx >> 9, lane = (idx >> 3) & 63, j = idx & 7;
        int wid = grp >> 2, nt = (grp >> 1) & 1, ks = grp & 1;
        col = wid * 32 + nt * 16 + (lane & 15);
        k   = ks * 32 + (lane >> 4) * 8 + j;
        w = W2[k * H2 + col];
        ph = W2h; pl = W2l;
    } else if (i < 53248) {
        idx = i - 12288;
        int grp = idx >> 9, lane = (idx >> 3) & 63, j = idx & 7;
        int w_ = grp / 20, rem = grp - w_ * 20;
        int ks = rem >> 2, nt = rem & 3;
        col = w_ * 64 + nt * 16 + (lane & 15);
        k   = ks * 32 + (lane >> 4) * 8 + j;
        w = (k < 132) ? W3[k * H3 + col] : 0.f;
        ph = W3h; pl = W3l;
    } else {
        idx = i - 53248;
        int grp = idx >> 9, lane = (idx >> 3) & 63, j = idx & 7;
        int w_ = grp >> 5, rem = grp & 31;
        int ks = rem >> 2, nt = rem & 3;
        col = w_ * 64 + nt * 16 + (lane & 15);
        k   = ks * 32 + (lane >> 4) * 8 + j;
        w = W4[k * H3 + col];
        ph = W4h; pl = W4l;
    }
    unsigned short h = f2bf(w);
    ph[idx] = h;
    pl[idx] = f2bf(w - bf2f(h));
}

// ---------------- pass 4: FUSED edge MLP + selector segment-mean + node MLP.
// NBN=16 (register-budget-verified, r7). 4 barriers/tile: the s4 barrier
// (between H2T write and selector read) is removed — wave wid writes H2T cols
// [wid*32, wid*32+32) in P3 and reads exactly those cols in P4 (intra-wave LDS
// dependency, ordered by lgkmcnt; no cross-wave hazard). s5 stays: next-tile P0
// overwrites the H2T region for ALL waves.
__global__ __launch_bounds__(256, 3) void edge_agg_kernel(
    const float* __restrict__ x, const int* __restrict__ eidx,
    const float* __restrict__ ea,
    const unsigned short* __restrict__ W1h, const unsigned short* __restrict__ W1l,
    const float* __restrict__ b1,
    const unsigned short* __restrict__ W2h, const unsigned short* __restrict__ W2l,
    const float* __restrict__ b2,
    const unsigned short* __restrict__ W3h, const unsigned short* __restrict__ W3l,
    const float* __restrict__ b3,
    const unsigned short* __restrict__ W4h, const unsigned short* __restrict__ W4l,
    const float* __restrict__ b4,
    const int* __restrict__ row_ptr, const int* __restrict__ perm,
    float* __restrict__ out)
{
    // uMem union: tile loop {Ahi|Alo|H1hi|H1lo [64][72] each} / {H2T hi|lo [128][72]}
    // epilogue: nA [16][168] hi/lo (5376 sh) then H [16][264] hi/lo at +5376
    __shared__ __align__(16) unsigned short uMem[4 * 64 * 72];     // 36864 B
    __shared__ __align__(16) int sNode[64];
    __shared__ int sPerm[2][64], sCol[2][64], sRP[NBN + 1];

    unsigned short* Ahi   = uMem;
    unsigned short* Alo   = uMem + 64 * 72;
    unsigned short* H1hi  = uMem + 2 * 64 * 72;
    unsigned short* H1lo  = uMem + 3 * 64 * 72;
    unsigned short* H2Thi = uMem;                 // [128][72]
    unsigned short* H2Tlo = uMem + 128 * 72;
    unsigned short* nAh   = uMem;                 // [16][168]
    unsigned short* nAl   = uMem + 16 * 168;
    unsigned short* Hh    = uMem + 2 * 16 * 168;  // [16][264]
    unsigned short* Hl    = uMem + 2 * 16 * 168 + 16 * 264;

    const int t    = threadIdx.x;
    const int lane = t & 63;
    const int wid  = t >> 6;
    const int cl   = lane & 15;
    const int lg   = lane >> 4;
    const int n0   = blockIdx.x * NBN;

    // issue tile-0 perm/col loads first
    int p0 = -1, c0 = 0;
    if (t < 64) {
        int b0  = row_ptr[n0];
        int e0r = row_ptr[n0 + NBN];
        if (b0 + t < e0r) p0 = perm[b0 + t];
        if (p0 >= 0) c0 = eidx[NE + p0];
    }

    if (t <= NBN) sRP[t] = row_ptr[n0 + t];

    // register-resident weight fragments (coalesced fragment-order layout)
    bfrag8 w1h_[2], w1l_[2], w2h_[2][2], w2l_[2][2];
    #pragma unroll
    for (int ks = 0; ks < 2; ks++) {
        const int off = ((wid * 2 + ks) * 64 + lane) * 8;
        w1h_[ks] = *(const bfrag8*)&W1h[off];
        w1l_[ks] = *(const bfrag8*)&W1l[off];
    }
    #pragma unroll
    for (int nt = 0; nt < 2; nt++)
        #pragma unroll
        for (int ks = 0; ks < 2; ks++) {
            const int off = (((wid * 2 + nt) * 2 + ks) * 64 + lane) * 8;
            w2h_[nt][ks] = *(const bfrag8*)&W2h[off];
            w2l_[nt][ks] = *(const bfrag8*)&W2l[off];
        }
    const float bias1 = b1[wid * 16 + cl];
    const float bias2[2] = { b2[wid * 32 + cl], b2[wid * 32 + 16 + cl] };

    // persistent per-node accumulator: wave wid owns cols [wid*32, wid*32+32)
    facc4 acc_sel[2];
    #pragma unroll
    for (int nt = 0; nt < 2; nt++) {
        acc_sel[nt][0] = 0.f; acc_sel[nt][1] = 0.f;
        acc_sel[nt][2] = 0.f; acc_sel[nt][3] = 0.f;
    }

    if (t < 64) { sPerm[0][t] = p0; sCol[0][t] = c0; }
    __syncthreads();

    const int base = sRP[0], cntE = sRP[NBN] - base;

    auto loadA = [&](float (&pv)[4][4], const int* sP, const int* sC) {
        #pragma unroll
        for (int r = 0; r < 4; r++) {
            const int e  = (t >> 4) + r * 16;
            const int k0 = (t & 15) * 4;
            const int ee = sP[e];
            if (ee >= 0) {
                if (k0 == 0) {
                    float4 xv = *(const float4*)&x[(size_t)sC[e] * XD];
                    pv[r][0] = xv.x; pv[r][1] = xv.y; pv[r][2] = xv.z; pv[r][3] = xv.w;
                } else {
                    const float* er = ea + (size_t)ee * ED;
                    #pragma unroll
                    for (int q = 0; q < 4; q++) {
                        int k = k0 + q;
                        pv[r][q] = (k < K1) ? er[k - XD] : 0.f;
                    }
                }
            } else {
                pv[r][0] = pv[r][1] = pv[r][2] = pv[r][3] = 0.f;
            }
        }
    };

    if (cntE > 0) {
        float pv[4][4];
        loadA(pv, sPerm[0], sCol[0]);
        int buf = 0;

        for (int tb = 0; tb < cntE; tb += 64) {
            const int nv   = min(64, cntE - tb);
            const int nbuf = buf ^ 1;

            int pp = -1;
            if (t < 64 && tb + 64 < cntE)
                pp = (tb + 64 + t < cntE) ? perm[base + tb + 64 + t] : -1;

            // ---- P0: stage A (overlays H2T; prev selector phase done at s5)
            #pragma unroll
            for (int r = 0; r < 4; r++) {
                const int e  = (t >> 4) + r * 16;
                const int k0 = (t & 15) * 4;
                u16x4 hv, lv;
                #pragma unroll
                for (int q = 0; q < 4; q++) {
                    unsigned short h = f2bf(pv[r][q]);
                    hv[q] = h;
                    lv[q] = f2bf(pv[r][q] - bf2f(h));
                }
                *(u16x4*)&Ahi[e * 72 + k0] = hv;
                *(u16x4*)&Alo[e * 72 + k0] = lv;
            }
            if (t < 64) {
                int nd = -1;
                if (t < nv) {
                    int idx = tb + t;
                    nd = 0;
                    #pragma unroll
                    for (int k = 1; k < NBN; k++) nd += ((sRP[k] - base) <= idx);
                }
                sNode[t] = nd;
            }
            __syncthreads();                                   // s1

            int pc = 0;
            if (t < 64 && pp >= 0) pc = eidx[NE + pp];

            // ---- P1: layer 1
            facc4 acc1[4];
            #pragma unroll
            for (int mt = 0; mt < 4; mt++) {
                acc1[mt][0] = bias1; acc1[mt][1] = bias1;
                acc1[mt][2] = bias1; acc1[mt][3] = bias1;
            }
            #pragma unroll
            for (int ks = 0; ks < 2; ks++) {
                #pragma unroll
                for (int mt = 0; mt < 4; mt++) {
                    const int ao = (mt * 16 + cl) * 72 + ks * 32 + lg * 8;
                    bfrag8 ah = *(const bfrag8*)&Ahi[ao];
                    bfrag8 al = *(const bfrag8*)&Alo[ao];
                    acc1[mt] = __builtin_amdgcn_mfma_f32_16x16x32_bf16(ah, w1h_[ks], acc1[mt], 0, 0, 0);
                    acc1[mt] = __builtin_amdgcn_mfma_f32_16x16x32_bf16(al, w1h_[ks], acc1[mt], 0, 0, 0);
                    acc1[mt] = __builtin_amdgcn_mfma_f32_16x16x32_bf16(ah, w1l_[ks], acc1[mt], 0, 0, 0);
                }
            }
            #pragma unroll
            for (int mt = 0; mt < 4; mt++)
                #pragma unroll
                for (int j = 0; j < 4; j++) {
                    float v = fmaxf(acc1[mt][j], 0.f);
                    unsigned short h = f2bf(v);
                    int m = mt * 16 + lg * 4 + j;
                    H1hi[m * 72 + wid * 16 + cl] = h;
                    H1lo[m * 72 + wid * 16 + cl] = f2bf(v - bf2f(h));
                }
            if (t < 64) { sPerm[nbuf][t] = pp; sCol[nbuf][t] = pc; }
            __syncthreads();                                   // s2

            // prefetch next tile's A values (overlaps L2 + H2T + selector phases)
            if (tb + 64 < cntE) loadA(pv, sPerm[nbuf], sCol[nbuf]);

            // ---- P2: layer 2
            facc4 acc2[4][2];
            #pragma unroll
            for (int mt = 0; mt < 4; mt++)
                #pragma unroll
                for (int nt = 0; nt < 2; nt++) {
                    acc2[mt][nt][0] = bias2[nt]; acc2[mt][nt][1] = bias2[nt];
                    acc2[mt][nt][2] = bias2[nt]; acc2[mt][nt][3] = bias2[nt];
                }
            #pragma unroll
            for (int ks = 0; ks < 2; ks++) {
                #pragma unroll
                for (int mt = 0; mt < 4; mt++) {
                    const int ao = (mt * 16 + cl) * 72 + ks * 32 + lg * 8;
                    bfrag8 ah = *(const bfrag8*)&H1hi[ao];
                    bfrag8 al = *(const bfrag8*)&H1lo[ao];
                    #pragma unroll
                    for (int nt = 0; nt < 2; nt++) {
                        acc2[mt][nt] = __builtin_amdgcn_mfma_f32_16x16x32_bf16(ah, w2h_[nt][ks], acc2[mt][nt], 0, 0, 0);
                        acc2[mt][nt] = __builtin_amdgcn_mfma_f32_16x16x32_bf16(al, w2h_[nt][ks], acc2[mt][nt], 0, 0, 0);
                        acc2[mt][nt] = __builtin_amdgcn_mfma_f32_16x16x32_bf16(ah, w2l_[nt][ks], acc2[mt][nt], 0, 0, 0);
                    }
                }
            }
            __syncthreads();                                   // s3: all uMem reads done

            // ---- P3: write relu(h2) hi/lo transposed [col][edge] (wave-private cols)
            #pragma unroll
            for (int mt = 0; mt < 4; mt++)
                #pragma unroll
                for (int nt = 0; nt < 2; nt++) {
                    const int c2 = wid * 32 + nt * 16 + cl;
                    u16x4 hv, lv;
                    #pragma unroll
                    for (int j = 0; j < 4; j++) {
                        float v = fmaxf(acc2[mt][nt][j], 0.f);
                        unsigned short h = f2bf(v);
                        hv[j] = h;
                        lv[j] = f2bf(v - bf2f(h));
                    }
                    const int eb = mt * 16 + lg * 4;
                    *(u16x4*)&H2Thi[c2 * 72 + eb] = hv;
                    *(u16x4*)&H2Tlo[c2 * 72 + eb] = lv;
                }
            // (no barrier: P4 reads only this wave's own columns)

            // ---- P4: selector MFMA — acc += SEL @ (H2hi + H2lo)
            #pragma unroll
            for (int ks = 0; ks < 2; ks++) {
                const int4* np = (const int4*)&sNode[ks * 32 + lg * 8];
                int4 na = np[0], nb = np[1];        // broadcast reads, conflict-free
                bfrag8 sf;
                sf[0] = (na.x == cl) ? (short)0x3F80 : (short)0;
                sf[1] = (na.y == cl) ? (short)0x3F80 : (short)0;
                sf[2] = (na.z == cl) ? (short)0x3F80 : (short)0;
                sf[3] = (na.w == cl) ? (short)0x3F80 : (short)0;
                sf[4] = (nb.x == cl) ? (short)0x3F80 : (short)0;
                sf[5] = (nb.y == cl) ? (short)0x3F80 : (short)0;
                sf[6] = (nb.z == cl) ? (short)0x3F80 : (short)0;
                sf[7] = (nb.w == cl) ? (short)0x3F80 : (short)0;
                #pragma unroll
                for (int nt = 0; nt < 2; nt++) {
                    const int hb = (wid * 32 + nt * 16 + cl) * 72 + ks * 32 + lg * 8;
                    bfrag8 hh = *(const bfrag8*)&H2Thi[hb];
                    bfrag8 hl = *(const bfrag8*)&H2Tlo[hb];
                    acc_sel[nt] = __builtin_amdgcn_mfma_f32_16x16x32_bf16(sf, hh, acc_sel[nt], 0, 0, 0);
                    acc_sel[nt] = __builtin_amdgcn_mfma_f32_16x16x32_bf16(sf, hl, acc_sel[nt], 0, 0, 0);
                }
            }
            __syncthreads();                                   // s5: uMem reads done
            buf = nbuf;
        }
    }

    // ================= node-MLP epilogue (fused node MLP, 16 nodes) =================
    __syncthreads();   // uniform (cntE block-uniform); protects uMem overlay

    // stage nA = [x(4) | mean(128) | 0-pad(28)] hi/lo from registers
    #pragma unroll
    for (int nt = 0; nt < 2; nt++)
        #pragma unroll
        for (int j = 0; j < 4; j++) {
            const int n = lg * 4 + j;
            const int deg = sRP[n + 1] - sRP[n];
            const float inv = (deg > 0) ? 1.f / (float)deg : 0.f;
            const float m = acc_sel[nt][j] * inv;
            unsigned short h = f2bf(m);
            const int k = 4 + wid * 32 + nt * 16 + cl;
            nAh[n * 168 + k] = h;
            nAl[n * 168 + k] = f2bf(m - bf2f(h));
        }
    if (t < 64) {
        const int n = t >> 2, k = t & 3;
        float xv = x[(size_t)(n0 + n) * XD + k];
        unsigned short h = f2bf(xv);
        nAh[n * 168 + k] = h;
        nAl[n * 168 + k] = f2bf(xv - bf2f(h));
    }
    for (int i = t; i < 448; i += 256) {       // k in [132,160)
        int n = i / 28, k = 132 + (i - n * 28);
        nAh[n * 168 + k] = 0;
        nAl[n * 168 + k] = 0;
    }
    __syncthreads();

    // GEMM1: [16 x 160] @ [160 x 256]; wave wid owns cols [wid*64, wid*64+64)
    facc4 na_[4];
    #pragma unroll
    for (int nt = 0; nt < 4; nt++) {
        float b = b3[wid * 64 + nt * 16 + cl];
        na_[nt][0] = b; na_[nt][1] = b; na_[nt][2] = b; na_[nt][3] = b;
    }
    #pragma unroll
    for (int ks = 0; ks < 5; ks++) {
        const int ao = cl * 168 + ks * 32 + lg * 8;
        bfrag8 ah = *(const bfrag8*)&nAh[ao];
        bfrag8 al = *(const bfrag8*)&nAl[ao];
        #pragma unroll
        for (int nt = 0; nt < 4; nt++) {
            const int wo = (((wid * 5 + ks) * 4 + nt) * 64 + lane) * 8;
            bfrag8 bh = *(const bfrag8*)&W3h[wo];
            bfrag8 bl = *(const bfrag8*)&W3l[wo];
            na_[nt] = __builtin_amdgcn_mfma_f32_16x16x32_bf16(ah, bh, na_[nt], 0, 0, 0);
            na_[nt] = __builtin_amdgcn_mfma_f32_16x16x32_bf16(al, bh, na_[nt], 0, 0, 0);
            na_[nt] = __builtin_amdgcn_mfma_f32_16x16x32_bf16(ah, bl, na_[nt], 0, 0, 0);
        }
    }
    // relu -> H [16][264] hi/lo (disjoint from nA region; no barrier needed before)
    #pragma unroll
    for (int nt = 0; nt < 4; nt++)
        #pragma unroll
        for (int j = 0; j < 4; j++) {
            float v = fmaxf(na_[nt][j], 0.f);
            const int r = lg * 4 + j;
            const int c = wid * 64 + nt * 16 + cl;
            unsigned short h = f2bf(v);
            Hh[r * 264 + c] = h;
            Hl[r * 264 + c] = f2bf(v - bf2f(h));
        }
    __syncthreads();

    // GEMM2: [16 x 256] @ [256 x 256] -> out
    facc4 nb_[4];
    #pragma unroll
    for (int nt = 0; nt < 4; nt++) {
        float b = b4[wid * 64 + nt * 16 + cl];
        nb_[nt][0] = b; nb_[nt][1] = b; nb_[nt][2] = b; nb_[nt][3] = b;
    }
    #pragma unroll
    for (int ks = 0; ks < 8; ks++) {
        const int ao = cl * 264 + ks * 32 + lg * 8;
        bfrag8 ah = *(const bfrag8*)&Hh[ao];
        bfrag8 al = *(const bfrag8*)&Hl[ao];
        #pragma unroll
        for (int nt = 0; nt < 4; nt++) {
            const int wo = (((wid * 8 + ks) * 4 + nt) * 64 + lane) * 8;
            bfrag8 bh = *(const bfrag8*)&W4h[wo];
            bfrag8 bl = *(const bfrag8*)&W4l[wo];
            nb_[nt] = __builtin_amdgcn_mfma_f32_16x16x32_bf16(ah, bh, nb_[nt], 0, 0, 0);
            nb_[nt] = __builtin_amdgcn_mfma_f32_16x16x32_bf16(al, bh, nb_[nt], 0, 0, 0);
            nb_[nt] = __builtin_amdgcn_mfma_f32_16x16x32_bf16(ah, bl, nb_[nt], 0, 0, 0);
        }
    }
    #pragma unroll
    for (int nt = 0; nt < 4; nt++)
        #pragma unroll
        for (int j = 0; j < 4; j++)
            out[(size_t)(n0 + lg * 4 + j) * H3 + wid * 64 + nt * 16 + cl] =
                fmaxf(nb_[nt][j], 0.f);
}

extern "C" void kernel_launch(void* const* d_in, const int* in_sizes, int n_in,
                              void* d_out, int out_size, void* d_ws, size_t ws_size,
                              hipStream_t stream) {
    const float* x    = (const float*)d_in[0];
    const int*   eidx = (const int*)  d_in[1];
    const float* ea   = (const float*)d_in[2];
    const float* W1   = (const float*)d_in[3];
    const float* b1   = (const float*)d_in[4];
    const float* W2   = (const float*)d_in[5];
    const float* b2   = (const float*)d_in[6];
    const float* W3   = (const float*)d_in[7];
    const float* b3   = (const float*)d_in[8];
    const float* W4   = (const float*)d_in[9];
    const float* b4   = (const float*)d_in[10];
    float* out = (float*)d_out;

    char* p = (char*)d_ws;
    int* perm     = (int*)p;  p += (size_t)NE * 4;
    int* rank     = (int*)p;  p += (size_t)NE * 4;          // dead after build
    int* row_ptr  = (int*)p;  p += ((size_t)NN + 8) * 4;
    int* cnt      = (int*)p;  p += (size_t)NN * 4;          // dead after scan1
    int* chunkSum = (int*)p;  p += 128 * 4;
    int* chunkOff = (int*)p;  p += 128 * 4;

    // weight bf16 hi/lo planes overlay rank (6.4 MB; dead after build_kernel)
    unsigned short* wp = (unsigned short*)rank;
    unsigned short* W1h_ = wp; wp += 64 * 64;
    unsigned short* W1l_ = wp; wp += 64 * 64;
    unsigned short* W2h_ = wp; wp += 128 * 64;
    unsigned short* W2l_ = wp; wp += 128 * 64;
    unsigned short* W3h_ = wp; wp += 256 * 160;
    unsigned short* W3l_ = wp; wp += 256 * 160;
    unsigned short* W4h_ = wp; wp += 256 * 256;
    unsigned short* W4l_ = wp; wp += 256 * 256;   // total 475136 B < 6.4 MB

    hipMemsetAsync(cnt, 0, (size_t)NN * 4, stream);

    hist_kernel <<<(NE + 255) / 256, 256, 0, stream>>>(eidx, cnt, rank);
    scan1_kernel<<<NCHUNK, 1024, 0, stream>>>(cnt, row_ptr, chunkSum);
    scan2_kernel<<<1, 64, 0, stream>>>(chunkSum, chunkOff);
    scan3_kernel<<<NCHUNK, 1024, 0, stream>>>(chunkOff, row_ptr);
    build_kernel<<<(NE + 255) / 256, 256, 0, stream>>>(eidx, row_ptr, rank, perm);
    prep_kernel <<<(4096 + 8192 + 40960 + 65536 + 255) / 256, 256, 0, stream>>>(
        W1, W2, W3, W4, W1h_, W1l_, W2h_, W2l_, W3h_, W3l_, W4h_, W4l_);
    edge_agg_kernel<<<NN / NBN, 256, 0, stream>>>(
        x, eidx, ea, W1h_, W1l_, b1, W2h_, W2l_, b2,
        W3h_, W3l_, b3, W4h_, W4l_, b4, row_ptr, perm, out);
}